// Round 7
// baseline (374.457 us; speedup 1.0000x reference)
//
#include <hip/hip_runtime.h>

#define N_ROWS 131072
#define KCODES 1024
#define DIM 64
#define BLOCK 256
#define ROWS_PB 128
#define KHALF (KCODES / 2)

// ||c||^2 for all codes, computed once by a tiny pre-kernel with the exact
// pairwise bit-formula the passing kernel used.
__device__ float g_c2[KCODES];

__global__ void __launch_bounds__(BLOCK)
c2_pre(const float* __restrict__ cb)
{
#pragma clang fp contract(off)
    const int code = blockIdx.x * BLOCK + threadIdx.x;
    const float* c = cb + code * DIM;
    float r0 = c[0]*c[0], r1 = c[1]*c[1], r2 = c[2]*c[2], r3 = c[3]*c[3];
    float r4 = c[4]*c[4], r5 = c[5]*c[5], r6 = c[6]*c[6], r7 = c[7]*c[7];
#pragma unroll
    for (int i = 1; i < 8; ++i) {
        r0 = r0 + c[i*8+0]*c[i*8+0];
        r1 = r1 + c[i*8+1]*c[i*8+1];
        r2 = r2 + c[i*8+2]*c[i*8+2];
        r3 = r3 + c[i*8+3]*c[i*8+3];
        r4 = r4 + c[i*8+4]*c[i*8+4];
        r5 = r5 + c[i*8+5]*c[i*8+5];
        r6 = r6 + c[i*8+6]*c[i*8+6];
        r7 = r7 + c[i*8+7]*c[i*8+7];
    }
    g_c2[code] = ((r0 + r1) + (r2 + r3)) + ((r4 + r5) + (r6 + r7));
}

typedef float f32x16 __attribute__((ext_vector_type(16)));
typedef float f32x2  __attribute__((ext_vector_type(2)));

// ROUND-7: round 6 proved the s_load codebook path (326us, 3x) but
// VGPR_Count=52 showed xr STILL rematerialized inside the k-loop — the
// round-5 fence only pins loads at a point; sinking into the loop keeps
// them after the fence (legal). Fix: pass every xr[d] through an opaque
// "+v" asm — the value's definition becomes un-rematerializable, so the
// compiler must keep it in a VGPR for the whole k-loop (or scratch-spill,
// which WRITE_SIZE would expose). Live set ~80 VGPR < 128 cap of
// waves_per_eu(4,4) -> 4 waves/SIMD, no spill.
__global__ void
__attribute__((amdgpu_flat_work_group_size(256, 256), amdgpu_waves_per_eu(4, 4)))
vq_main(const float* __restrict__ h,
        const float* __restrict__ cb,
        float* __restrict__ z_out,
        float* __restrict__ q_out)
{
    __shared__ float mbd[ROWS_PB];    // khalf0 best dist
    __shared__ int   mbk[ROWS_PB];    // khalf0 best idx
    __shared__ int   s_idx[ROWS_PB];  // final idx for q gather

    const int tid   = threadIdx.x;
    const int lane  = tid & 63;
    const int wave  = tid >> 6;            // 0..3
    const int khalf = wave >> 1;           // 0: k in [0,512), 1: [512,1024)
    const int rloc  = (wave & 1) * 64 + lane;   // 0..127
    const int row0  = blockIdx.x * ROWS_PB;
    const int row   = row0 + rloc;
    const int bb    = row >> 12;
    const int yx    = row & 4095;

    // ---- x row into registers (coalesced across lanes for each d) ----
    float xr[DIM];
    {
        const float* hb = h + (size_t)bb * (DIM * 4096) + yx;
#pragma unroll
        for (int d = 0; d < DIM; ++d)
            xr[d] = hb[(size_t)d * 4096];
    }
    // Opaque per-element pin: xr[d] becomes an un-rematerializable VGPR def.
#pragma unroll
    for (int d = 0; d < DIM; ++d)
        asm volatile("" : "+v"(xr[d]));

    // ---- Sv = ||x||^2, exact pairwise bit-formula as before ----
    float Sv;
    {
#pragma clang fp contract(off)
        float r0 = xr[0]*xr[0], r1 = xr[1]*xr[1], r2 = xr[2]*xr[2], r3 = xr[3]*xr[3];
        float r4 = xr[4]*xr[4], r5 = xr[5]*xr[5], r6 = xr[6]*xr[6], r7 = xr[7]*xr[7];
#pragma unroll
        for (int i = 1; i < 8; ++i) {
            r0 = r0 + xr[i*8+0]*xr[i*8+0];
            r1 = r1 + xr[i*8+1]*xr[i*8+1];
            r2 = r2 + xr[i*8+2]*xr[i*8+2];
            r3 = r3 + xr[i*8+3]*xr[i*8+3];
            r4 = r4 + xr[i*8+4]*xr[i*8+4];
            r5 = r5 + xr[i*8+5]*xr[i*8+5];
            r6 = r6 + xr[i*8+6]*xr[i*8+6];
            r7 = r7 + xr[i*8+7]*xr[i*8+7];
        }
        Sv = ((r0 + r1) + (r2 + r3)) + ((r4 + r5) + (r6 + r7));
    }

    // Wave-uniform k-base, provably scalar via readfirstlane.
    const int kb = __builtin_amdgcn_readfirstlane(khalf) * KHALF;
    const float* c2base = (const float*)g_c2;

    float bd = 3.4e38f;
    int   bk = 0;

#pragma unroll 1
    for (int kp = 0; kp < KHALF; kp += 2) {
        const int k = kb + kp;
        const float* cp  = cb + (size_t)k * DIM;      // uniform: kernarg + scalar
        const float* c2p = c2base + k;

        // ---- chunk 0: dims 0..31 of codes k (offs 0,64) and k+1 (256,320) ----
        f32x16 a0, b0, a1, b1; f32x2 cc;
        asm volatile(
            "s_load_dwordx16 %0, %5, 0\n\t"
            "s_load_dwordx16 %1, %5, 256\n\t"
            "s_load_dwordx16 %2, %5, 64\n\t"
            "s_load_dwordx16 %3, %5, 320\n\t"
            "s_load_dwordx2  %4, %6, 0\n\t"
            "s_waitcnt lgkmcnt(0)"
            : "=&s"(a0), "=&s"(b0), "=&s"(a1), "=&s"(b1), "=&s"(cc)
            : "s"(cp), "s"(c2p));

        float accA = 0.0f, accB = 0.0f;
#pragma unroll
        for (int j = 0; j < 16; ++j) {
            accA = __builtin_fmaf(xr[j], a0[j], accA);
            accB = __builtin_fmaf(xr[j], b0[j], accB);
        }
#pragma unroll
        for (int j = 0; j < 16; ++j) {
            accA = __builtin_fmaf(xr[16 + j], a1[j], accA);
            accB = __builtin_fmaf(xr[16 + j], b1[j], accB);
        }

        // ---- chunk 1: dims 32..63 of codes k (128,192) and k+1 (384,448) ----
        f32x16 a2, b2, a3, b3;
        asm volatile(
            "s_load_dwordx16 %0, %4, 128\n\t"
            "s_load_dwordx16 %1, %4, 384\n\t"
            "s_load_dwordx16 %2, %4, 192\n\t"
            "s_load_dwordx16 %3, %4, 448\n\t"
            "s_waitcnt lgkmcnt(0)"
            : "=&s"(a2), "=&s"(b2), "=&s"(a3), "=&s"(b3)
            : "s"(cp));
#pragma unroll
        for (int j = 0; j < 16; ++j) {
            accA = __builtin_fmaf(xr[32 + j], a2[j], accA);
            accB = __builtin_fmaf(xr[32 + j], b2[j], accB);
        }
#pragma unroll
        for (int j = 0; j < 16; ++j) {
            accA = __builtin_fmaf(xr[48 + j], a3[j], accA);
            accB = __builtin_fmaf(xr[48 + j], b3[j], accB);
        }

        // ---- exact epilogue; A (k) before B (k+1) keeps first-index ties ----
        {
#pragma clang fp contract(off)
            const float tA  = 2.0f * accA;   // exact
            const float uA  = Sv - tA;       // rounded like np
            const float d2A = uA + cc[0];
            if (d2A < bd) { bd = d2A; bk = k; }
            const float tB  = 2.0f * accB;
            const float uB  = Sv - tB;
            const float d2B = uB + cc[1];
            if (d2B < bd) { bd = d2B; bk = k + 1; }
        }
    }

    // ---- merge k-halves: khalf0 wins ties (smaller k) => np first-index ----
    if (khalf == 0) { mbd[rloc] = bd; mbk[rloc] = bk; }
    __syncthreads();
    if (khalf == 1) {
        const float d0  = mbd[rloc];
        const int   kk0 = mbk[rloc];
        const int   fk  = (bd < d0) ? bk : kk0;
        z_out[row]  = (float)fk;
        s_idx[rloc] = fk;
    }
    __syncthreads();

    // ---- q gather: bit-exact codebook rows, coalesced float4 stores ----
    const float4* cb4 = (const float4*)cb;
    float4* q4 = (float4*)q_out;
#pragma unroll
    for (int it = 0; it < 8; ++it) {
        const int slot = it * BLOCK + tid;    // 0..2047
        const int rl   = slot >> 4;           // row 0..127
        const int c4   = slot & 15;
        q4[(size_t)(row0 + rl) * 16 + c4] = cb4[(size_t)s_idx[rl] * 16 + c4];
    }
}

extern "C" void kernel_launch(void* const* d_in, const int* in_sizes, int n_in,
                              void* d_out, int out_size, void* d_ws, size_t ws_size,
                              hipStream_t stream) {
    const float* h  = (const float*)d_in[0];
    const float* cb = (const float*)d_in[1];
    float* out   = (float*)d_out;
    float* z_out = out;              // 131072 floats
    float* q_out = out + N_ROWS;     // 131072*64 floats
    (void)d_ws; (void)ws_size;

    c2_pre<<<dim3(KCODES / BLOCK), dim3(BLOCK), 0, stream>>>(cb);
    vq_main<<<dim3(N_ROWS / ROWS_PB), dim3(BLOCK), 0, stream>>>(h, cb, z_out, q_out);
}

// Round 8
// 345.000 us; speedup vs baseline: 1.0854x; 1.0854x over previous
//
#include <hip/hip_runtime.h>

#define N_ROWS 131072
#define KCODES 1024
#define DIM 64
#define BLOCK 256
#define ROWS_PB 256
#define KCHUNK 128
#define NCHUNK (KCODES / KCHUNK)

// ||c||^2 for all codes, computed once with the exact pairwise bit-formula.
__device__ float g_c2[KCODES];

__global__ void __launch_bounds__(BLOCK)
c2_pre(const float* __restrict__ cb)
{
#pragma clang fp contract(off)
    const int code = blockIdx.x * BLOCK + threadIdx.x;
    const float* c = cb + code * DIM;
    float r0 = c[0]*c[0], r1 = c[1]*c[1], r2 = c[2]*c[2], r3 = c[3]*c[3];
    float r4 = c[4]*c[4], r5 = c[5]*c[5], r6 = c[6]*c[6], r7 = c[7]*c[7];
#pragma unroll
    for (int i = 1; i < 8; ++i) {
        r0 = r0 + c[i*8+0]*c[i*8+0];
        r1 = r1 + c[i*8+1]*c[i*8+1];
        r2 = r2 + c[i*8+2]*c[i*8+2];
        r3 = r3 + c[i*8+3]*c[i*8+3];
        r4 = r4 + c[i*8+4]*c[i*8+4];
        r5 = r5 + c[i*8+5]*c[i*8+5];
        r6 = r6 + c[i*8+6]*c[i*8+6];
        r7 = r7 + c[i*8+7]*c[i*8+7];
    }
    g_c2[code] = ((r0 + r1) + (r2 + r3)) + ((r4 + r5) + (r6 + r7));
}

// ROUND-8: round 6/7 showed the SMEM broadcast path is structurally
// throughput-bound: the codebook (256 KB) always misses the scalar K$,
// whose limited miss-in-flight capacity caps delivery at ~2.6 B/cyc per
// K$ group => 537 MB of SMEM traffic = the whole 333 us. Fix: broadcast
// via LDS instead. Uniform-address ds_read_b128 broadcasts 16 B to all
// 64 lanes at full rate (same-address = no conflict, ~120 cyc latency,
// per-CU pipe). Codebook staged chunk-wise (128 codes = 32 KB) into
// double-buffered LDS; c2 chunk staged alongside.
//
// Row-per-lane, NO k-split: 4 waves x 64 rows, each wave scans all 1024
// codes for its own rows => no merge, ties are naturally first-index.
// Grid 512 = exactly 2 blocks/CU (LDS-capped); staging of one block
// overlaps compute of the other. Per code-pair: 32 uniform ds_read_b128
// + 128 fma (ILP-2 chains) + exact epilogue — VALU-issue-bound.
__global__ void
__attribute__((amdgpu_flat_work_group_size(256, 256), amdgpu_waves_per_eu(2, 2)))
vq_main(const float* __restrict__ h,
        const float* __restrict__ cb,
        float* __restrict__ z_out,
        float* __restrict__ q_out)
{
    __shared__ float cs[2][KCHUNK * DIM];   // 2 x 32 KB code chunks
    __shared__ float c2s[2][KCHUNK];        // 2 x 512 B ||c||^2 chunks
    __shared__ int   s_idx[ROWS_PB];        // final idx for q gather

    const int tid  = threadIdx.x;
    const int row0 = blockIdx.x * ROWS_PB;
    const int row  = row0 + tid;            // lane == local row (4 waves x 64)
    const int bb   = row >> 12;             // 4096 % 256 == 0 -> bb uniform per block
    const int yx   = row & 4095;

    // ---- x row into registers (coalesced: lanes = consecutive yx) ----
    float xr[DIM];
    {
        const float* hb = h + (size_t)bb * (DIM * 4096) + yx;
#pragma unroll
        for (int d = 0; d < DIM; ++d)
            xr[d] = hb[(size_t)d * 4096];
    }
    // Opaque pin (round-7): keeps xr un-rematerializable, proven harmless.
#pragma unroll
    for (int d = 0; d < DIM; ++d)
        asm volatile("" : "+v"(xr[d]));

    // ---- Sv = ||x||^2, exact pairwise bit-formula as before ----
    float Sv;
    {
#pragma clang fp contract(off)
        float r0 = xr[0]*xr[0], r1 = xr[1]*xr[1], r2 = xr[2]*xr[2], r3 = xr[3]*xr[3];
        float r4 = xr[4]*xr[4], r5 = xr[5]*xr[5], r6 = xr[6]*xr[6], r7 = xr[7]*xr[7];
#pragma unroll
        for (int i = 1; i < 8; ++i) {
            r0 = r0 + xr[i*8+0]*xr[i*8+0];
            r1 = r1 + xr[i*8+1]*xr[i*8+1];
            r2 = r2 + xr[i*8+2]*xr[i*8+2];
            r3 = r3 + xr[i*8+3]*xr[i*8+3];
            r4 = r4 + xr[i*8+4]*xr[i*8+4];
            r5 = r5 + xr[i*8+5]*xr[i*8+5];
            r6 = r6 + xr[i*8+6]*xr[i*8+6];
            r7 = r7 + xr[i*8+7]*xr[i*8+7];
        }
        Sv = ((r0 + r1) + (r2 + r3)) + ((r4 + r5) + (r6 + r7));
    }

    // ---- stage chunk 0 ----
    {
        const float4* src = (const float4*)cb;            // chunk 0 base
        float4* dst = (float4*)cs[0];
#pragma unroll
        for (int i = 0; i < 8; ++i)
            dst[i * BLOCK + tid] = src[i * BLOCK + tid];
        if (tid < KCHUNK) c2s[0][tid] = g_c2[tid];
    }
    __syncthreads();

    float bd = 3.4e38f;
    int   bk = 0;

#pragma unroll 1
    for (int c = 0; c < NCHUNK; ++c) {
        const int cur = c & 1;

        // stage next chunk into the other buffer (overlaps compute)
        if (c + 1 < NCHUNK) {
            const float4* src = (const float4*)(cb + (size_t)(c + 1) * KCHUNK * DIM);
            float4* dst = (float4*)cs[cur ^ 1];
#pragma unroll
            for (int i = 0; i < 8; ++i)
                dst[i * BLOCK + tid] = src[i * BLOCK + tid];
            if (tid < KCHUNK) c2s[cur ^ 1][tid] = g_c2[(c + 1) * KCHUNK + tid];
        }

        // ---- compute over current chunk: pairs of codes, ILP-2 ----
        const float* cbase = cs[cur];
#pragma unroll 1
        for (int kk = 0; kk < KCHUNK; kk += 2) {
            const int k = c * KCHUNK + kk;
            const float* c0 = cbase + kk * DIM;
            const float* c1 = c0 + DIM;
            const float c2A = c2s[cur][kk];
            const float c2B = c2s[cur][kk + 1];

            float accA = 0.0f, accB = 0.0f;
#pragma unroll
            for (int j = 0; j < 16; ++j) {
                const float4 a = *(const float4*)(c0 + j * 4);   // uniform -> broadcast
                const float4 b = *(const float4*)(c1 + j * 4);
                accA = __builtin_fmaf(xr[4*j+0], a.x, accA);
                accA = __builtin_fmaf(xr[4*j+1], a.y, accA);
                accA = __builtin_fmaf(xr[4*j+2], a.z, accA);
                accA = __builtin_fmaf(xr[4*j+3], a.w, accA);
                accB = __builtin_fmaf(xr[4*j+0], b.x, accB);
                accB = __builtin_fmaf(xr[4*j+1], b.y, accB);
                accB = __builtin_fmaf(xr[4*j+2], b.z, accB);
                accB = __builtin_fmaf(xr[4*j+3], b.w, accB);
            }

            {
#pragma clang fp contract(off)
                const float tA  = 2.0f * accA;   // exact
                const float uA  = Sv - tA;       // rounded like np
                const float d2A = uA + c2A;
                if (d2A < bd) { bd = d2A; bk = k; }       // strict < => first index
                const float tB  = 2.0f * accB;
                const float uB  = Sv - tB;
                const float d2B = uB + c2B;
                if (d2B < bd) { bd = d2B; bk = k + 1; }
            }
        }
        __syncthreads();   // next buffer staged AND current fully consumed
    }

    // ---- outputs: z directly, idx to LDS for the q gather ----
    z_out[row] = (float)bk;
    s_idx[tid] = bk;
    __syncthreads();

    // ---- q gather: bit-exact codebook rows, coalesced float4 stores ----
    const float4* cb4 = (const float4*)cb;
    float4* q4 = (float4*)q_out;
#pragma unroll
    for (int it = 0; it < 16; ++it) {
        const int slot = it * BLOCK + tid;    // 0..4095
        const int rl   = slot >> 4;           // row 0..255
        const int c4   = slot & 15;
        q4[(size_t)(row0 + rl) * 16 + c4] = cb4[(size_t)s_idx[rl] * 16 + c4];
    }
}

extern "C" void kernel_launch(void* const* d_in, const int* in_sizes, int n_in,
                              void* d_out, int out_size, void* d_ws, size_t ws_size,
                              hipStream_t stream) {
    const float* h  = (const float*)d_in[0];
    const float* cb = (const float*)d_in[1];
    float* out   = (float*)d_out;
    float* z_out = out;              // 131072 floats
    float* q_out = out + N_ROWS;     // 131072*64 floats
    (void)d_ws; (void)ws_size;

    c2_pre<<<dim3(KCODES / BLOCK), dim3(BLOCK), 0, stream>>>(cb);
    vq_main<<<dim3(N_ROWS / ROWS_PB), dim3(BLOCK), 0, stream>>>(h, cb, z_out, q_out);
}